// Round 1
// baseline (697.059 us; speedup 1.0000x reference)
//
#include <hip/hip_runtime.h>
#include <math.h>

#define NN 768
#define H 8
#define F 16
#define HF 128
#define EIN 64
#define EOUT 64
#define E_EDGES 24576
#define SLOPE 0.2f
#define EPS 1e-5f

__device__ __forceinline__ float leaky(float x){ return x >= 0.f ? x : SLOPE*x; }
__device__ __forceinline__ float elu1(float x){ return x > 0.f ? x : expm1f(x); }

// ---------------- K0: node projections ----------------
// npj = x@Wp^T ; ss/st score reductions ; outn_pre = x@Wskip^T (skip path)
__global__ void k_proj(const float* __restrict__ x, const float* __restrict__ Wp,
                       const float* __restrict__ Wskip, const float* __restrict__ ssrc,
                       const float* __restrict__ stgt,
                       float* __restrict__ npj, float* __restrict__ ss, float* __restrict__ st,
                       float* __restrict__ outn_pre){
  __shared__ float xsh[HF];
  __shared__ float ps[HF], pt[HF];
  int i = blockIdx.x, c = threadIdx.x;
  xsh[c] = x[i*HF + c];
  __syncthreads();
  float a = 0.f, b = 0.f;
  #pragma unroll 4
  for(int k=0;k<HF;k++){ float xv = xsh[k]; a += xv*Wp[c*HF+k]; b += xv*Wskip[c*HF+k]; }
  npj[i*HF+c] = a;
  outn_pre[i*HF+c] = b;
  ps[c] = a*ssrc[c]; pt[c] = a*stgt[c];
  __syncthreads();
  if(c < H){
    float s1=0.f, s2=0.f;
    #pragma unroll
    for(int f=0; f<F; f++){ s1 += ps[c*F+f]; s2 += pt[c*F+f]; }
    ss[i*H+c]=s1; st[i*H+c]=s2;
  }
}

// ---------------- K1: big fused edge-projection -> logits ----------------
// logits[h,i,j] = leaky(se[i,j,h]) + leaky(ss[i,h]+st[j,h]) + mask[i,j]
// where se = sum_f leaky(edges[i,j,:]@Wp2[h*16+f,:] + bp2)*sce[h,f]
#define TJ 128
__global__ __launch_bounds__(256,2) void k_edge_logits(
    const float* __restrict__ edges, const float* __restrict__ Wp2,
    const float* __restrict__ bp2, const float* __restrict__ sce,
    const float* __restrict__ ss, const float* __restrict__ st,
    const float* __restrict__ mask, float* __restrict__ logits){
  __shared__ float4 esh[TJ*16];   // 32 KB, XOR-swizzled by ((row>>2)&7)
  __shared__ float4 wsh[HF*16];   // 32 KB, XOR-swizzled by (row>>4)
  __shared__ float stsh[TJ*H];
  __shared__ float bp2sh[HF], scesh[HF], masksh[TJ];
  int i  = blockIdx.x / 6;
  int jt = blockIdx.x % 6;
  int j0 = jt*TJ;
  int tid = threadIdx.x;

  const float4* W4 = (const float4*)Wp2;            // 2048 float4
  #pragma unroll
  for(int t=0;t<8;t++){
    int fi = tid + t*256;
    int row = fi >> 4, k4 = fi & 15;
    wsh[row*16 + (k4 ^ (row>>4))] = W4[fi];
  }
  const float4* Eg = (const float4*)(edges + (size_t)i*NN*EIN + (size_t)j0*EIN);
  #pragma unroll
  for(int t=0;t<8;t++){
    int fi = tid + t*256;
    int row = fi >> 4, k4 = fi & 15;
    esh[row*16 + (k4 ^ ((row>>2)&7))] = Eg[fi];
  }
  #pragma unroll
  for(int t=0;t<4;t++){ int idx = tid + t*256; stsh[idx] = st[j0*H + idx]; }
  if(tid < HF){ bp2sh[tid] = bp2[tid]; scesh[tid] = sce[tid]; }
  if(tid < TJ) masksh[tid] = mask[i*NN + j0 + tid];
  __syncthreads();

  int h = tid & 7, jg = tid >> 3;   // jg 0..31, 4 j's each
  float acc[4][16];
  #pragma unroll
  for(int a=0;a<4;a++)
    #pragma unroll
    for(int f=0;f<16;f++) acc[a][f]=0.f;

  #pragma unroll 4
  for(int k4=0;k4<16;k4++){
    int se_ = k4 ^ (jg&7);
    float4 e0 = esh[(jg*4+0)*16 + se_];
    float4 e1 = esh[(jg*4+1)*16 + se_];
    float4 e2 = esh[(jg*4+2)*16 + se_];
    float4 e3 = esh[(jg*4+3)*16 + se_];
    int sw_ = k4 ^ h;
    #pragma unroll
    for(int f=0;f<16;f++){
      float4 w = wsh[(h*16+f)*16 + sw_];
      acc[0][f] += e0.x*w.x + e0.y*w.y + e0.z*w.z + e0.w*w.w;
      acc[1][f] += e1.x*w.x + e1.y*w.y + e1.z*w.z + e1.w*w.w;
      acc[2][f] += e2.x*w.x + e2.y*w.y + e2.z*w.z + e2.w*w.w;
      acc[3][f] += e3.x*w.x + e3.y*w.y + e3.z*w.z + e3.w*w.w;
    }
  }

  float ssv = ss[i*H + h];
  #pragma unroll
  for(int a=0;a<4;a++){
    int jl = jg*4 + a;
    float se = 0.f;
    #pragma unroll
    for(int f=0;f<16;f++){
      float p = acc[a][f] + bp2sh[h*16+f];
      se += leaky(p) * scesh[h*16+f];
    }
    float val = leaky(se) + leaky(ssv + stsh[jl*H + h]) + masksh[jl];
    logits[((size_t)h*NN + i)*NN + (j0 + jl)] = val;
  }
}

// ---------------- K2: row softmax in-place ----------------
__global__ void k_softmax(float* __restrict__ logits){
  size_t base = (size_t)blockIdx.x * NN;
  int tid = threadIdx.x;
  float v0 = logits[base+tid], v1 = logits[base+tid+256], v2 = logits[base+tid+512];
  float m = fmaxf(v0, fmaxf(v1,v2));
  #pragma unroll
  for(int o=1;o<64;o<<=1) m = fmaxf(m, __shfl_xor(m,o));
  __shared__ float red[4];
  if((tid&63)==0) red[tid>>6]=m;
  __syncthreads();
  m = fmaxf(fmaxf(red[0],red[1]),fmaxf(red[2],red[3]));
  float e0=expf(v0-m), e1=expf(v1-m), e2=expf(v2-m);
  float s = e0+e1+e2;
  #pragma unroll
  for(int o=1;o<64;o<<=1) s += __shfl_xor(s,o);
  __shared__ float red2[4];
  if((tid&63)==0) red2[tid>>6]=s;
  __syncthreads();
  s = red2[0]+red2[1]+red2[2]+red2[3];
  float inv = 1.0f/s;
  logits[base+tid]=e0*inv; logits[base+tid+256]=e1*inv; logits[base+tid+512]=e2*inv;
}

// ---------------- K3: outn_pre += einsum('hij,jhf->ihf') ----------------
__global__ void k_einsum(const float* __restrict__ attn, const float* __restrict__ npj,
                         float* __restrict__ outn_pre){
  int i = blockIdx.x, c = threadIdx.x;     // 128 threads
  int h = c >> 4;
  const float* arow = attn + ((size_t)h*NN + i)*NN;
  float acc = outn_pre[i*HF + c];
  #pragma unroll 8
  for(int j=0;j<NN;j++) acc += arow[j] * npj[j*HF + c];
  outn_pre[i*HF + c] = acc;
}

// ---------------- K4: node BN stats ----------------
__global__ void k_bn_node_stats(const float* __restrict__ outn_pre, float* __restrict__ stats){
  int c = threadIdx.x & 127, half = threadIdx.x >> 7;
  int r0 = blockIdx.x*16 + half*8;
  float s1=0.f, s2=0.f;
  #pragma unroll
  for(int r=0;r<8;r++){ float v = outn_pre[(r0+r)*HF + c]; s1+=v; s2+=v*v; }
  __shared__ float l1[256], l2[256];
  l1[threadIdx.x]=s1; l2[threadIdx.x]=s2;
  __syncthreads();
  if(threadIdx.x < 128){
    s1 = l1[threadIdx.x] + l1[threadIdx.x+128];
    s2 = l2[threadIdx.x] + l2[threadIdx.x+128];
    atomicAdd(&stats[c], s1); atomicAdd(&stats[HF + c], s2);
  }
}

// ---------------- K5: node BN apply + bias + elu -> d_out outn ----------------
__global__ void k_bn_node_apply(const float* __restrict__ outn_pre, const float* __restrict__ stats,
                                const float* __restrict__ g, const float* __restrict__ b,
                                const float* __restrict__ nbias, float* __restrict__ outn){
  int idx = blockIdx.x*256 + threadIdx.x;
  int c = idx & 127;
  float m  = stats[c] * (1.f/NN);
  float var = stats[HF+c]*(1.f/NN) - m*m;
  float xv = outn_pre[idx];
  float y = g[c]*(xv - m)/sqrtf(var + EPS) + b[c] + nbias[c];
  outn[idx] = elu1(y);
}

// ---------------- K6: sparse edge MLP -> oe_pre + edge BN stats ----------------
__global__ __launch_bounds__(256,1) void k_sparse_oe(
    const float* __restrict__ sef, const int* __restrict__ eidx,
    const float* __restrict__ outn,
    const float* __restrict__ Wf1, const float* __restrict__ bf1,
    const float* __restrict__ Wf2, const float* __restrict__ Wf3,
    const float* __restrict__ Wes,
    float* __restrict__ oe_pre, float* __restrict__ stats){
  __shared__ float w1[64*65];
  __shared__ float w2[64*129];
  __shared__ float w3[64*129];
  __shared__ float we[64*65];
  __shared__ float b1sh[64];
  __shared__ float sefsh[4][64];
  __shared__ float ddsh[4][128];
  __shared__ float msh[4][64], rsh[4][64];
  __shared__ float r1[256], r2[256];
  int tid = threadIdx.x;
  for(int idx = tid; idx < 64*64; idx += 256){ int o = idx>>6, k = idx&63; w1[o*65+k] = Wf1[idx]; we[o*65+k] = Wes[idx]; }
  for(int idx = tid; idx < 64*128; idx += 256){ int o = idx>>7, k = idx&127; w2[o*129+k] = Wf2[idx]; w3[o*129+k] = Wf3[idx]; }
  if(tid<64) b1sh[tid] = bf1[tid];
  int e0 = blockIdx.x * 16;
  float s1 = 0.f, s2 = 0.f;
  int ee = tid >> 6, o = tid & 63;
  for(int eg=0; eg<4; eg++){
    int ebase = e0 + eg*4;
    { int k = tid & 63, e4 = tid >> 6; sefsh[e4][k] = sef[(ebase+e4)*64 + k]; }
    #pragma unroll
    for(int t=0;t<2;t++){
      int idx = tid + t*256; int e4 = idx >> 7, c = idx & 127;
      int ed = ebase + e4;
      int si = eidx[ed*2], sj = eidx[ed*2+1];
      float d = outn[si*HF + c] - outn[sj*HF + c];
      ddsh[e4][c] = d*d;
    }
    __syncthreads();
    float m = b1sh[o], r = 0.f, oes = 0.f;
    #pragma unroll 4
    for(int k=0;k<64;k++){ float sv = sefsh[ee][k]; m += sv*w1[o*65+k]; oes += sv*we[o*65+k]; }
    #pragma unroll 4
    for(int c=0;c<128;c++){ r += ddsh[ee][c]*w2[o*129+c]; }
    m = leaky(m); r = leaky(r);
    msh[ee][o] = m; rsh[ee][o] = r;
    __syncthreads();
    float oe = oes;
    #pragma unroll 4
    for(int k=0;k<64;k++){ oe += msh[ee][k]*w3[o*129+k] + rsh[ee][k]*w3[o*129+64+k]; }
    oe_pre[(size_t)(ebase+ee)*64 + o] = oe;
    s1 += oe; s2 += oe*oe;
    __syncthreads();
  }
  r1[tid] = s1; r2[tid] = s2;
  __syncthreads();
  if(tid < 64){
    float a1 = r1[tid] + r1[tid+64] + r1[tid+128] + r1[tid+192];
    float a2 = r2[tid] + r2[tid+64] + r2[tid+128] + r2[tid+192];
    atomicAdd(&stats[256 + tid], a1);
    atomicAdd(&stats[320 + tid], a2);
  }
}

// ---------------- K7: edge BN apply + elu -> d_out oe ----------------
__global__ void k_bn_edge_apply(const float* __restrict__ oe_pre, const float* __restrict__ stats,
                                const float* __restrict__ g, const float* __restrict__ b,
                                float* __restrict__ oe_out){
  int idx = blockIdx.x*256 + threadIdx.x;
  int o = idx & 63;
  float m = stats[256+o] * (1.f/E_EDGES);
  float var = stats[320+o]*(1.f/E_EDGES) - m*m;
  float xv = oe_pre[idx];
  float y = g[o]*(xv-m)/sqrtf(var+EPS) + b[o];
  oe_out[idx] = elu1(y);
}

// ---------------- K8: ie nonzero fill (only unmasked (i,j)) ----------------
__global__ __launch_bounds__(256) void k_ie_fill(
    const float* __restrict__ edges, const float* __restrict__ mask,
    const float* __restrict__ Wf4, const float* __restrict__ bf4,
    float* __restrict__ ie){
  __shared__ float w4[64*65];
  __shared__ float b4sh[64];
  __shared__ int list[NN];
  __shared__ int lcnt;
  int i = blockIdx.x, tid = threadIdx.x;
  if(tid==0) lcnt = 0;
  for(int idx=tid; idx<64*64; idx+=256){ int o=idx>>6,k=idx&63; w4[o*65+k]=Wf4[idx]; }
  if(tid<64) b4sh[tid]=bf4[tid];
  __syncthreads();
  for(int t=0;t<3;t++){
    int j = tid + t*256;
    if(mask[i*NN+j] == 0.0f){ int p = atomicAdd(&lcnt,1); list[p]=j; }
  }
  __syncthreads();
  int cnt = lcnt;
  float inv;
  if(cnt == 0){
    for(int t=0;t<3;t++) list[tid+t*256] = tid+t*256;
    cnt = NN; inv = 1.0f/NN;
    __syncthreads();
  } else inv = 1.0f/cnt;
  int o = tid & 63, jj4 = tid >> 6;
  for(int base=0; base<cnt; base+=4){
    int li = base + jj4;
    if(li < cnt){
      int j = list[li];
      const float* er = edges + ((size_t)i*NN + j)*EIN;
      float acc = b4sh[o];
      #pragma unroll 8
      for(int k=0;k<64;k++) acc += er[k]*w4[o*65+k];
      ie[((size_t)i*NN + j)*EIN + o] = acc * inv;
    }
  }
}

// ---------------- K9: scatter oe into ie (last-duplicate wins) ----------------
__global__ void k_winner(const int* __restrict__ eidx, int* __restrict__ winner){
  int e = blockIdx.x*256 + threadIdx.x;
  if(e < E_EDGES){
    int si = eidx[e*2], sj = eidx[e*2+1];
    atomicMax(&winner[si*NN+sj], e);
  }
}
__global__ void k_scatter(const int* __restrict__ eidx, const int* __restrict__ winner,
                          const float* __restrict__ oe, float* __restrict__ ie){
  int idx = blockIdx.x*256 + threadIdx.x;
  int e = idx >> 6, o = idx & 63;
  int si = eidx[e*2], sj = eidx[e*2+1];
  if(winner[si*NN+sj] == e) ie[((size_t)si*NN+sj)*EIN + o] = oe[(size_t)e*64+o];
}

// ---------------- K10: indices -> float ----------------
__global__ void k_idxf(const int* __restrict__ eidx, float* __restrict__ outf){
  int idx = blockIdx.x*256 + threadIdx.x;
  if(idx < E_EDGES*2) outf[idx] = (float)eidx[idx];
}

extern "C" void kernel_launch(void* const* d_in, const int* in_sizes, int n_in,
                              void* d_out, int out_size, void* d_ws, size_t ws_size,
                              hipStream_t stream){
  (void)in_sizes; (void)n_in; (void)out_size; (void)d_ws; (void)ws_size;
  const float* x     = (const float*)d_in[0];
  const float* edges = (const float*)d_in[1];
  const float* mask  = (const float*)d_in[2];
  const float* sef   = (const float*)d_in[3];
  const int*   eidx  = (const int*)d_in[4];
  const float* Wp    = (const float*)d_in[5];
  const float* Wp2   = (const float*)d_in[6];
  const float* bp2   = (const float*)d_in[7];
  const float* ssrc  = (const float*)d_in[8];
  const float* stgt  = (const float*)d_in[9];
  const float* sce   = (const float*)d_in[10];
  const float* Wskip = (const float*)d_in[11];
  const float* nbias = (const float*)d_in[12];
  const float* bng   = (const float*)d_in[13];
  const float* bnb   = (const float*)d_in[14];
  const float* Wf1   = (const float*)d_in[15];
  const float* bf1   = (const float*)d_in[16];
  const float* Wf2   = (const float*)d_in[17];
  const float* Wf3   = (const float*)d_in[18];
  const float* Wf4   = (const float*)d_in[19];
  const float* bf4   = (const float*)d_in[20];
  const float* Wes   = (const float*)d_in[21];
  const float* beg   = (const float*)d_in[22];
  const float* beb   = (const float*)d_in[23];

  float* out      = (float*)d_out;
  float* out_outn = out;                    // 98304
  float* out_ie   = out + 98304;            // 37748736
  float* out_mask = out + 37847040;         // 589824
  float* out_oe   = out + 38436864;         // 1572864
  float* out_idx  = out + 40009728;         // 49152

  // scratch carved out of the (not yet written) ie region
  float* s_logits = out_ie;                 // 4718592
  float* s_npj    = out_ie + 4718592;       // 98304
  float* s_ss     = s_npj + 98304;          // 6144
  float* s_st     = s_ss + 6144;            // 6144
  float* s_opre   = s_st + 6144;            // 98304
  float* s_oepre  = s_opre + 98304;         // 1572864
  float* s_stats  = s_oepre + 1572864;      // 512 (node s1/s2, edge s1/s2)
  int*   winner   = (int*)out_mask;         // scratch until mask copied at end

  hipMemsetAsync(s_stats, 0, 512*sizeof(float), stream);
  hipMemsetAsync(winner, 0xFF, (size_t)NN*NN*sizeof(int), stream);

  k_proj<<<NN, 128, 0, stream>>>(x, Wp, Wskip, ssrc, stgt, s_npj, s_ss, s_st, s_opre);
  k_edge_logits<<<NN*6, 256, 0, stream>>>(edges, Wp2, bp2, sce, s_ss, s_st, mask, s_logits);
  k_softmax<<<H*NN, 256, 0, stream>>>(s_logits);
  k_einsum<<<NN, 128, 0, stream>>>(s_logits, s_npj, s_opre);
  k_bn_node_stats<<<48, 256, 0, stream>>>(s_opre, s_stats);
  k_bn_node_apply<<<384, 256, 0, stream>>>(s_opre, s_stats, bng, bnb, nbias, out_outn);
  k_sparse_oe<<<E_EDGES/16, 256, 0, stream>>>(sef, eidx, out_outn, Wf1, bf1, Wf2, Wf3, Wes, s_oepre, s_stats);
  k_bn_edge_apply<<<6144, 256, 0, stream>>>(s_oepre, s_stats, beg, beb, out_oe);
  // all scratch in ie region consumed; now build ie
  hipMemsetAsync(out_ie, 0, (size_t)NN*NN*EIN*sizeof(float), stream);
  k_ie_fill<<<NN, 256, 0, stream>>>(edges, mask, Wf4, bf4, out_ie);
  k_winner<<<96, 256, 0, stream>>>(eidx, winner);
  k_scatter<<<6144, 256, 0, stream>>>(eidx, winner, out_oe, out_ie);
  hipMemcpyAsync(out_mask, mask, (size_t)NN*NN*sizeof(float), hipMemcpyDeviceToDevice, stream);
  k_idxf<<<192, 256, 0, stream>>>(eidx, out_idx);
}

// Round 3
// 542.356 us; speedup vs baseline: 1.2852x; 1.2852x over previous
//
#include <hip/hip_runtime.h>
#include <math.h>

#define NN 768
#define H 8
#define F 16
#define HF 128
#define EIN 64
#define EOUT 64
#define E_EDGES 24576
#define SLOPE 0.2f
#define EPS 1e-5f

__device__ __forceinline__ float leaky(float x){ return x >= 0.f ? x : SLOPE*x; }
__device__ __forceinline__ float elu1(float x){ return x > 0.f ? x : expm1f(x); }

// ---------------- K0: node projections ----------------
__global__ void k_proj(const float* __restrict__ x, const float* __restrict__ Wp,
                       const float* __restrict__ Wskip, const float* __restrict__ ssrc,
                       const float* __restrict__ stgt,
                       float* __restrict__ npj, float* __restrict__ ss, float* __restrict__ st,
                       float* __restrict__ outn_pre){
  __shared__ float xsh[HF];
  __shared__ float ps[HF], pt[HF];
  int i = blockIdx.x, c = threadIdx.x;
  xsh[c] = x[i*HF + c];
  __syncthreads();
  float a = 0.f, b = 0.f;
  #pragma unroll 4
  for(int k=0;k<HF;k++){ float xv = xsh[k]; a += xv*Wp[c*HF+k]; b += xv*Wskip[c*HF+k]; }
  npj[i*HF+c] = a;
  outn_pre[i*HF+c] = b;
  ps[c] = a*ssrc[c]; pt[c] = a*stgt[c];
  __syncthreads();
  if(c < H){
    float s1=0.f, s2=0.f;
    #pragma unroll
    for(int f=0; f<F; f++){ s1 += ps[c*F+f]; s2 += pt[c*F+f]; }
    ss[i*H+c]=s1; st[i*H+c]=s2;
  }
}

// ---------------- K_list: per-row stable list of unmasked j ----------------
__global__ void k_list(const float* __restrict__ mask, int* __restrict__ lists, int* __restrict__ cnt){
  int w = threadIdx.x >> 6, lane = threadIdx.x & 63;
  int i = blockIdx.x*4 + w;
  int base = 0;
  const float* mrow = mask + (size_t)i*NN;
  int* lrow = lists + (size_t)i*NN;
  for(int t=0;t<12;t++){
    int j = t*64 + lane;
    bool un = (mrow[j] == 0.0f);
    unsigned long long b = __ballot(un);
    if(un) lrow[base + __popcll(b & ((1ull<<lane)-1ull))] = j;
    base += (int)__popcll(b);
  }
  if(base == 0){                      // all-masked fallback: softmax over full row
    for(int t=0;t<12;t++) lrow[t*64+lane] = t*64+lane;
    base = NN;
  }
  if(lane==0) cnt[i] = base;
}

// ---------------- K1': sparse fused edge-projection -> compact logits ----------------
// logitc[i,h,s] = leaky(se) + leaky(ss[i,h]+st[j,h]) + mask[i,j],  j = lists[i][s]
__global__ __launch_bounds__(256,4) void k_logits_sparse(
    const float* __restrict__ edges, const float* __restrict__ Wp2,
    const float* __restrict__ bp2, const float* __restrict__ sce,
    const float* __restrict__ ss, const float* __restrict__ st,
    const float* __restrict__ mask,
    const int* __restrict__ lists, const int* __restrict__ cnt,
    float* __restrict__ logitc){
  __shared__ float4 wsh[HF*16];      // 32KB, linear [row][k4]; bank-spread via XOR'd read order
  __shared__ float4 esh[4][2][16];   // per-wave staging, 2 slots
  __shared__ float bsh[HF], scsh[HF];
  int i = blockIdx.x, tid = threadIdx.x;
  const float4* W4 = (const float4*)Wp2;
  #pragma unroll
  for(int t=0;t<8;t++) wsh[tid + t*256] = W4[tid + t*256];
  if(tid < HF){ bsh[tid]=bp2[tid]; scsh[tid]=sce[tid]; }
  __syncthreads();
  int w = tid>>6, lane = tid&63;
  int n = cnt[i];
  float ss0 = ss[i*H + (lane>>4)];
  float ss1 = ss[i*H + 4 + (lane>>4)];
  const int* lrow = lists + (size_t)i*NN;
  for(int s0 = w*2; s0 < n; s0 += 8){
    int s1 = s0 + 1;
    int j0 = lrow[s0];
    int j1 = lrow[(s1 < n) ? s1 : s0];
    if(lane < 32){
      int which = lane >> 4, k4 = lane & 15;
      int jj = which ? j1 : j0;
      esh[w][which][k4] = ((const float4*)(edges + ((size_t)i*NN + jj)*EIN))[k4];
    }
    asm volatile("s_waitcnt lgkmcnt(0) vmcnt(0)" ::: "memory");
    __builtin_amdgcn_sched_barrier(0);
    float a00=0.f,a01=0.f,a10=0.f,a11=0.f;
    #pragma unroll
    for(int t=0;t<16;t++){
      int q = t ^ (lane & 15);
      float4 e0 = esh[w][0][q];
      float4 e1 = esh[w][1][q];
      float4 w0 = wsh[lane*16 + q];
      float4 w1 = wsh[(lane+64)*16 + q];
      a00 += e0.x*w0.x + e0.y*w0.y + e0.z*w0.z + e0.w*w0.w;
      a01 += e1.x*w0.x + e1.y*w0.y + e1.z*w0.z + e1.w*w0.w;
      a10 += e0.x*w1.x + e0.y*w1.y + e0.z*w1.z + e0.w*w1.w;
      a11 += e1.x*w1.x + e1.y*w1.y + e1.z*w1.z + e1.w*w1.w;
    }
    float p;
    p = a00 + bsh[lane];    float v0  = leaky(p)*scsh[lane];
    p = a01 + bsh[lane];    float v0b = leaky(p)*scsh[lane];
    p = a10 + bsh[lane+64]; float v1  = leaky(p)*scsh[lane+64];
    p = a11 + bsh[lane+64]; float v1b = leaky(p)*scsh[lane+64];
    #pragma unroll
    for(int o=1;o<16;o<<=1){
      v0 += __shfl_xor(v0,o); v0b += __shfl_xor(v0b,o);
      v1 += __shfl_xor(v1,o); v1b += __shfl_xor(v1b,o);
    }
    if((lane & 15) == 0){
      int h = lane >> 4;
      float m0 = mask[(size_t)i*NN + j0];
      logitc[((size_t)i*H + h)*NN + s0]     = leaky(v0) + leaky(ss0 + st[j0*H + h]) + m0;
      logitc[((size_t)i*H + h + 4)*NN + s0] = leaky(v1) + leaky(ss1 + st[j0*H + h + 4]) + m0;
      if(s1 < n){
        float m1 = mask[(size_t)i*NN + j1];
        logitc[((size_t)i*H + h)*NN + s1]     = leaky(v0b) + leaky(ss0 + st[j1*H + h]) + m1;
        logitc[((size_t)i*H + h + 4)*NN + s1] = leaky(v1b) + leaky(ss1 + st[j1*H + h + 4]) + m1;
      }
    }
  }
}

// ---------------- K2': compact softmax, 32-lane group per (i,h) ----------------
__global__ void k_softmax_c(float* __restrict__ logitc, const int* __restrict__ cnt){
  int i = blockIdx.x;
  int g = threadIdx.x >> 5, l = threadIdx.x & 31;
  int n = cnt[i];
  float* row = logitc + ((size_t)i*H + g)*NN;
  float m = -1e30f;
  for(int s=l; s<n; s+=32) m = fmaxf(m, row[s]);
  #pragma unroll
  for(int o=1;o<32;o<<=1) m = fmaxf(m, __shfl_xor(m, o, 32));
  float sum = 0.f;
  for(int s=l; s<n; s+=32){ float e = expf(row[s]-m); row[s]=e; sum+=e; }
  #pragma unroll
  for(int o=1;o<32;o<<=1) sum += __shfl_xor(sum, o, 32);
  float inv = 1.f/sum;
  for(int s=l; s<n; s+=32) row[s] *= inv;
}

// ---------------- K3': sparse einsum ----------------
__global__ void k_einsum_c(const float* __restrict__ attnc, const int* __restrict__ lists,
                           const int* __restrict__ cnt, const float* __restrict__ npj,
                           float* __restrict__ opre){
  int i = blockIdx.x, c = threadIdx.x;
  int h = c >> 4;
  int n = cnt[i];
  const int* lrow = lists + (size_t)i*NN;
  const float* arow = attnc + ((size_t)i*H + h)*NN;
  float acc = opre[i*HF + c];
  #pragma unroll 4
  for(int s=0; s<n; s++) acc += arow[s] * npj[lrow[s]*HF + c];
  opre[i*HF+c] = acc;
}

// ---------------- K4: node BN stats ----------------
__global__ void k_bn_node_stats(const float* __restrict__ outn_pre, float* __restrict__ stats){
  int c = threadIdx.x & 127, half = threadIdx.x >> 7;
  int r0 = blockIdx.x*16 + half*8;
  float s1=0.f, s2=0.f;
  #pragma unroll
  for(int r=0;r<8;r++){ float v = outn_pre[(r0+r)*HF + c]; s1+=v; s2+=v*v; }
  __shared__ float l1[256], l2[256];
  l1[threadIdx.x]=s1; l2[threadIdx.x]=s2;
  __syncthreads();
  if(threadIdx.x < 128){
    s1 = l1[threadIdx.x] + l1[threadIdx.x+128];
    s2 = l2[threadIdx.x] + l2[threadIdx.x+128];
    atomicAdd(&stats[c], s1); atomicAdd(&stats[HF + c], s2);
  }
}

// ---------------- K5: node BN apply ----------------
__global__ void k_bn_node_apply(const float* __restrict__ outn_pre, const float* __restrict__ stats,
                                const float* __restrict__ g, const float* __restrict__ b,
                                const float* __restrict__ nbias, float* __restrict__ outn){
  int idx = blockIdx.x*256 + threadIdx.x;
  int c = idx & 127;
  float m  = stats[c] * (1.f/NN);
  float var = stats[HF+c]*(1.f/NN) - m*m;
  float xv = outn_pre[idx];
  float y = g[c]*(xv - m)/sqrtf(var + EPS) + b[c] + nbias[c];
  outn[idx] = elu1(y);
}

// ---------------- K6: sparse edge MLP (96 edges/block, 1 block/CU) ----------------
__global__ __launch_bounds__(256,1) void k_sparse_oe(
    const float* __restrict__ sef, const int* __restrict__ eidx,
    const float* __restrict__ outn,
    const float* __restrict__ Wf1, const float* __restrict__ bf1,
    const float* __restrict__ Wf2, const float* __restrict__ Wf3,
    const float* __restrict__ Wes,
    float* __restrict__ oe_pre, float* __restrict__ stats){
  __shared__ float w1[64*65];
  __shared__ float w2[64*129];
  __shared__ float w3[64*129];
  __shared__ float we[64*65];
  __shared__ float b1sh[64];
  __shared__ float sefsh[4][64];
  __shared__ float ddsh[4][128];
  __shared__ float msh[4][64], rsh[4][64];
  __shared__ float r1[256], r2[256];
  int tid = threadIdx.x;
  for(int idx = tid; idx < 64*64; idx += 256){ int o = idx>>6, k = idx&63; w1[o*65+k] = Wf1[idx]; we[o*65+k] = Wes[idx]; }
  for(int idx = tid; idx < 64*128; idx += 256){ int o = idx>>7, k = idx&127; w2[o*129+k] = Wf2[idx]; w3[o*129+k] = Wf3[idx]; }
  if(tid<64) b1sh[tid] = bf1[tid];
  int e0 = blockIdx.x * 96;
  float s1 = 0.f, s2 = 0.f;
  int ee = tid >> 6, o = tid & 63;
  for(int eg=0; eg<24; eg++){
    int ebase = e0 + eg*4;
    { int k = tid & 63, e4 = tid >> 6; sefsh[e4][k] = sef[(ebase+e4)*64 + k]; }
    #pragma unroll
    for(int t=0;t<2;t++){
      int idx = tid + t*256; int e4 = idx >> 7, c = idx & 127;
      int ed = ebase + e4;
      int si = eidx[ed*2], sj = eidx[ed*2+1];
      float d = outn[si*HF + c] - outn[sj*HF + c];
      ddsh[e4][c] = d*d;
    }
    __syncthreads();
    float m = b1sh[o], r = 0.f, oes = 0.f;
    #pragma unroll 4
    for(int k=0;k<64;k++){ float sv = sefsh[ee][k]; m += sv*w1[o*65+k]; oes += sv*we[o*65+k]; }
    #pragma unroll 4
    for(int c=0;c<128;c++){ r += ddsh[ee][c]*w2[o*129+c]; }
    m = leaky(m); r = leaky(r);
    msh[ee][o] = m; rsh[ee][o] = r;
    __syncthreads();
    float oe = oes;
    #pragma unroll 4
    for(int k=0;k<64;k++){ oe += msh[ee][k]*w3[o*129+k] + rsh[ee][k]*w3[o*129+64+k]; }
    oe_pre[(size_t)(ebase+ee)*64 + o] = oe;
    s1 += oe; s2 += oe*oe;
    __syncthreads();
  }
  r1[tid] = s1; r2[tid] = s2;
  __syncthreads();
  if(tid < 64){
    float a1 = r1[tid] + r1[tid+64] + r1[tid+128] + r1[tid+192];
    float a2 = r2[tid] + r2[tid+64] + r2[tid+128] + r2[tid+192];
    atomicAdd(&stats[256 + tid], a1);
    atomicAdd(&stats[320 + tid], a2);
  }
}

// ---------------- K7: edge BN apply ----------------
__global__ void k_bn_edge_apply(const float* __restrict__ oe_pre, const float* __restrict__ stats,
                                const float* __restrict__ g, const float* __restrict__ b,
                                float* __restrict__ oe_out){
  int idx = blockIdx.x*256 + threadIdx.x;
  int o = idx & 63;
  float m = stats[256+o] * (1.f/E_EDGES);
  float var = stats[320+o]*(1.f/E_EDGES) - m*m;
  float xv = oe_pre[idx];
  float y = g[o]*(xv-m)/sqrtf(var+EPS) + b[o];
  oe_out[idx] = elu1(y);
}

// ---------------- K8: ie nonzero fill (self-contained mask scan) ----------------
__global__ __launch_bounds__(256) void k_ie_fill(
    const float* __restrict__ edges, const float* __restrict__ mask,
    const float* __restrict__ Wf4, const float* __restrict__ bf4,
    float* __restrict__ ie){
  __shared__ float w4[64*65];
  __shared__ float b4sh[64];
  __shared__ int list[NN];
  __shared__ int lcnt;
  int i = blockIdx.x, tid = threadIdx.x;
  if(tid==0) lcnt = 0;
  for(int idx=tid; idx<64*64; idx+=256){ int o=idx>>6,k=idx&63; w4[o*65+k]=Wf4[idx]; }
  if(tid<64) b4sh[tid]=bf4[tid];
  __syncthreads();
  for(int t=0;t<3;t++){
    int j = tid + t*256;
    if(mask[i*NN+j] == 0.0f){ int p = atomicAdd(&lcnt,1); list[p]=j; }
  }
  __syncthreads();
  int cnt = lcnt;
  float inv;
  if(cnt == 0){
    for(int t=0;t<3;t++) list[tid+t*256] = tid+t*256;
    cnt = NN; inv = 1.0f/NN;
    __syncthreads();
  } else inv = 1.0f/cnt;
  int o = tid & 63, jj4 = tid >> 6;
  for(int base=0; base<cnt; base+=4){
    int li = base + jj4;
    if(li < cnt){
      int j = list[li];
      const float* er = edges + ((size_t)i*NN + j)*EIN;
      float acc = b4sh[o];
      #pragma unroll 8
      for(int k=0;k<64;k++) acc += er[k]*w4[o*65+k];
      ie[((size_t)i*NN + j)*EIN + o] = acc * inv;
    }
  }
}

// ---------------- K9: scatter oe into ie (last-duplicate wins) ----------------
__global__ void k_winner(const int* __restrict__ eidx, int* __restrict__ winner){
  int e = blockIdx.x*256 + threadIdx.x;
  if(e < E_EDGES){
    int si = eidx[e*2], sj = eidx[e*2+1];
    atomicMax(&winner[si*NN+sj], e);
  }
}
__global__ void k_scatter(const int* __restrict__ eidx, const int* __restrict__ winner,
                          const float* __restrict__ oe, float* __restrict__ ie){
  int idx = blockIdx.x*256 + threadIdx.x;
  int e = idx >> 6, o = idx & 63;
  int si = eidx[e*2], sj = eidx[e*2+1];
  if(winner[si*NN+sj] == e) ie[((size_t)si*NN+sj)*EIN + o] = oe[(size_t)e*64+o];
}

// ---------------- K10: indices -> float ----------------
__global__ void k_idxf(const int* __restrict__ eidx, float* __restrict__ outf){
  int idx = blockIdx.x*256 + threadIdx.x;
  if(idx < E_EDGES*2) outf[idx] = (float)eidx[idx];
}

extern "C" void kernel_launch(void* const* d_in, const int* in_sizes, int n_in,
                              void* d_out, int out_size, void* d_ws, size_t ws_size,
                              hipStream_t stream){
  (void)in_sizes; (void)n_in; (void)out_size; (void)d_ws; (void)ws_size;
  const float* x     = (const float*)d_in[0];
  const float* edges = (const float*)d_in[1];
  const float* mask  = (const float*)d_in[2];
  const float* sef   = (const float*)d_in[3];
  const int*   eidx  = (const int*)d_in[4];
  const float* Wp    = (const float*)d_in[5];
  const float* Wp2   = (const float*)d_in[6];
  const float* bp2   = (const float*)d_in[7];
  const float* ssrc  = (const float*)d_in[8];
  const float* stgt  = (const float*)d_in[9];
  const float* sce   = (const float*)d_in[10];
  const float* Wskip = (const float*)d_in[11];
  const float* nbias = (const float*)d_in[12];
  const float* bng   = (const float*)d_in[13];
  const float* bnb   = (const float*)d_in[14];
  const float* Wf1   = (const float*)d_in[15];
  const float* bf1   = (const float*)d_in[16];
  const float* Wf2   = (const float*)d_in[17];
  const float* Wf3   = (const float*)d_in[18];
  const float* Wf4   = (const float*)d_in[19];
  const float* bf4   = (const float*)d_in[20];
  const float* Wes   = (const float*)d_in[21];
  const float* beg   = (const float*)d_in[22];
  const float* beb   = (const float*)d_in[23];

  float* out      = (float*)d_out;
  float* out_outn = out;                    // 98304
  float* out_ie   = out + 98304;            // 37748736
  float* out_mask = out + 37847040;         // 589824
  float* out_oe   = out + 38436864;         // 1572864
  float* out_idx  = out + 40009728;         // 49152

  // scratch carved out of the (not yet written) ie region
  float* s_logitc = out_ie;                 // 4718592
  float* s_npj    = out_ie + 4718592;       // 98304
  float* s_ss     = s_npj + 98304;          // 6144
  float* s_st     = s_ss + 6144;            // 6144
  float* s_opre   = s_st + 6144;            // 98304
  float* s_oepre  = s_opre + 98304;         // 1572864
  float* s_stats  = s_oepre + 1572864;      // 512
  int*   s_lists  = (int*)(s_stats + 512);  // 2359296
  int*   s_cnt    = s_lists + 2359296;      // 768
  int*   winner   = (int*)out_mask;         // scratch until mask copied at end

  hipMemsetAsync(s_stats, 0, 512*sizeof(float), stream);
  hipMemsetAsync(winner, 0xFF, (size_t)NN*NN*sizeof(int), stream);

  k_list<<<NN/4, 256, 0, stream>>>(mask, s_lists, s_cnt);
  k_proj<<<NN, 128, 0, stream>>>(x, Wp, Wskip, ssrc, stgt, s_npj, s_ss, s_st, s_opre);
  k_logits_sparse<<<NN, 256, 0, stream>>>(edges, Wp2, bp2, sce, s_ss, s_st, mask, s_lists, s_cnt, s_logitc);
  k_softmax_c<<<NN, 256, 0, stream>>>(s_logitc, s_cnt);
  k_einsum_c<<<NN, 128, 0, stream>>>(s_logitc, s_lists, s_cnt, s_npj, s_opre);
  k_bn_node_stats<<<48, 256, 0, stream>>>(s_opre, s_stats);
  k_bn_node_apply<<<384, 256, 0, stream>>>(s_opre, s_stats, bng, bnb, nbias, out_outn);
  k_sparse_oe<<<E_EDGES/96, 256, 0, stream>>>(sef, eidx, out_outn, Wf1, bf1, Wf2, Wf3, Wes, s_oepre, s_stats);
  k_bn_edge_apply<<<6144, 256, 0, stream>>>(s_oepre, s_stats, beg, beb, out_oe);
  // all ie-region scratch consumed; now build ie
  hipMemsetAsync(out_ie, 0, (size_t)NN*NN*EIN*sizeof(float), stream);
  k_ie_fill<<<NN, 256, 0, stream>>>(edges, mask, Wf4, bf4, out_ie);
  k_winner<<<96, 256, 0, stream>>>(eidx, winner);
  k_scatter<<<6144, 256, 0, stream>>>(eidx, winner, out_oe, out_ie);
  hipMemcpyAsync(out_mask, mask, (size_t)NN*NN*sizeof(float), hipMemcpyDeviceToDevice, stream);
  k_idxf<<<192, 256, 0, stream>>>(eidx, out_idx);
}